// Round 8
// baseline (848.883 us; speedup 1.0000x reference)
//
#include <hip/hip_runtime.h>

#define BB 8
#define NN 2048
#define FIN0 16
#define EE 64
#define HH 4
#define DD 16
#define HIDN 128
#define AA 4

// ---------------- adjacency -> blocked bitmask, TRANSPOSED: mbT[b][kblk][q] ----------------
__global__ __launch_bounds__(256) void k_mask(const float* __restrict__ adj, unsigned long long* __restrict__ mbT) {
    const int ITER = 32;
    for (int it = 0; it < ITER; it++) {
        long long idx = ((long long)blockIdx.x * ITER + it) * 256 + threadIdx.x;  // b*N*N + r*N + k
        int k = (int)(idx & (NN - 1));
        int r = (int)((idx >> 11) & (NN - 1));
        int b = (int)(idx >> 22);
        float a = adj[idx];
        bool blocked = (a == 0.0f) && (k != r);
        unsigned long long m = __ballot(blocked);
        if ((threadIdx.x & 63) == 0) mbT[((long long)b * 32 + (k >> 6)) * NN + r] = m;
    }
}

// ---------------- fold weights: CW = {wq,wk,wv}@in_w (Q cols pre-scaled), WO = mha_ow@op_w ----------------
#define QSCALE 0.36067376022224085f   // 0.25 * log2(e)
__device__ __forceinline__ float sfeat(int f) {
    return (f == 4 || f == 14 || f == 15) ? 1.0f : ((f == 5) ? (1.0f / 300.0f) : 0.02f);
}
__global__ __launch_bounds__(256) void k_wcomb(
        const float* __restrict__ wq0, const float* __restrict__ wk0, const float* __restrict__ wv0,
        const float* __restrict__ inw0, const float* __restrict__ inb0,
        const float* __restrict__ mow0, const float* __restrict__ mob0,
        const float* __restrict__ opw0, const float* __restrict__ opb0,
        const float* __restrict__ wq1, const float* __restrict__ wk1, const float* __restrict__ wv1,
        const float* __restrict__ inw1, const float* __restrict__ inb1,
        const float* __restrict__ mow1, const float* __restrict__ mob1,
        const float* __restrict__ opw1, const float* __restrict__ opb1,
        float* __restrict__ CW0, float* __restrict__ WO0, float* __restrict__ bO0, float* __restrict__ bQ0,
        float* __restrict__ CW1, float* __restrict__ WO1, float* __restrict__ bO1, float* __restrict__ bQ1) {
    int ly = blockIdx.y;
    int fin = ly ? EE : FIN0;
    const float* wq = ly ? wq1 : wq0; const float* wk = ly ? wk1 : wk0; const float* wv = ly ? wv1 : wv0;
    const float* inw = ly ? inw1 : inw0; const float* inb = ly ? inb1 : inb0;
    const float* mow = ly ? mow1 : mow0; const float* mob = ly ? mob1 : mob0;
    const float* opw = ly ? opw1 : opw0; const float* opb = ly ? opb1 : opb0;
    float* CW = ly ? CW1 : CW0; float* WO = ly ? WO1 : WO0;
    float* bO = ly ? bO1 : bO0; float* bQ = ly ? bQ1 : bQ0;

    int t = blockIdx.x * 256 + threadIdx.x;
    int t1 = fin * 192;
    int t2 = t1 + 4096;
    int t3 = t2 + 64;
    int t4 = t3 + 192;
    if (t < t1) {
        int f = t / 192, j = t % 192;
        const float* w = (j < 64) ? wq : ((j < 128) ? wk : wv);
        float acc = 0.f;
        for (int kk = 0; kk < 64; kk++) acc += w[f * 64 + kk] * inw[kk * 192 + j];
        if (j < 64) acc *= QSCALE;
        if (ly == 0) acc *= sfeat(f);
        CW[t] = acc;
    } else if (t < t2) {
        int u = t - t1; int i = u >> 6, j = u & 63;
        float acc = 0.f;
        for (int kk = 0; kk < 64; kk++) acc += mow[i * 64 + kk] * opw[kk * 64 + j];
        WO[u] = acc;
    } else if (t < t3) {
        int j = t - t2;
        float acc = opb[j];
        for (int kk = 0; kk < 64; kk++) acc += mob[kk] * opw[kk * 64 + j];
        bO[j] = acc;
    } else if (t < t4) {
        int j = t - t3;
        bQ[j] = inb[j] * ((j < 64) ? QSCALE : 1.0f);
    }
}

// ---------------- fused QKV projection (layer 0): X[B*N][fin] @ CW + bQ -> Q,K,V [B][H][N][D] ----------------
template <int FINP>
__global__ __launch_bounds__(256) void k_qkv(const float* __restrict__ X, const float* __restrict__ CW,
                                             const float* __restrict__ bQ,
                                             float* __restrict__ Q, float* __restrict__ K, float* __restrict__ V) {
    int lane = threadIdx.x & 63;
    int quarter = threadIdx.x >> 6;
    int row = blockIdx.x * 64 + lane;
    int b = row >> 11, n = row & (NN - 1);
    float xr[FINP];
    const float4* xp = (const float4*)(X + (long long)row * FINP);
#pragma unroll
    for (int i = 0; i < FINP / 4; i++) {
        float4 v = xp[i];
        xr[4 * i] = v.x; xr[4 * i + 1] = v.y; xr[4 * i + 2] = v.z; xr[4 * i + 3] = v.w;
    }
    for (int jq = 0; jq < 12; jq++) {
        int j = quarter * 48 + jq * 4;
        float4 acc = *(const float4*)(bQ + j);
#pragma unroll
        for (int f = 0; f < FINP; f++) {
            float4 w = *(const float4*)(CW + f * 192 + j);
            acc.x = fmaf(xr[f], w.x, acc.x);
            acc.y = fmaf(xr[f], w.y, acc.y);
            acc.z = fmaf(xr[f], w.z, acc.z);
            acc.w = fmaf(xr[f], w.w, acc.w);
        }
        int which = j >> 6, c = j & 63, h = c >> 4, d = c & 15;
        float* dst = (which == 0) ? Q : ((which == 1) ? K : V);
        *(float4*)(dst + (((long long)(b * HH + h) * NN + n) * DD + d)) = acc;
    }
}

// ---------------- attention v8: 256-thr blocks, launch_bounds(256,1) breaks the 128-VGPR wall ----------------
// 4 waves = 4 k-quarters, rq=2 q-rows/lane (block covers 128 q). K AND V stream from global as
// wave-uniform broadcast loads with A/B register double-buffers at 2-row prefetch distance —
// zero LDS in the main loop (LDS only for the 34.8 KB epilogue reduction -> 2 blocks/CU,
// 8 waves/CU). VGPR budget with min-1-wave/EU is 512: the dbuf stays in registers (v5/v6's
// spill failure mode was the 128-cap of 512-thread workgroups).
__global__ __launch_bounds__(256, 1)
void k_attn(const float* __restrict__ Q, const float* __restrict__ K,
            const float* __restrict__ V,
            const unsigned long long* __restrict__ mbT,
            float* __restrict__ O) {
    __shared__ float smem[4 * 2 * 64 * 17];            // 34816 B: epilogue reduction only
    int lane = threadIdx.x & 63;
    int w = threadIdx.x >> 6;                          // k-quarter owner (512 rows)
    int qb = blockIdx.x, h = blockIdx.y, b = blockIdx.z;
    int qbase = qb * 128;

    const float* Qbh = Q + (long long)(b * HH + h) * NN * DD;
    const float* Kb  = K + (long long)(b * HH + h) * NN * DD;
    const float* Vb  = V + (long long)(b * HH + h) * NN * DD;
    const unsigned long long* mrow = mbT + (long long)b * 32 * NN;

    float4 qf[2][4];
#pragma unroll
    for (int rq = 0; rq < 2; rq++) {
        const float4* qp = (const float4*)(Qbh + (long long)(qbase + rq * 64 + lane) * DD);
#pragma unroll
        for (int j = 0; j < 4; j++) qf[rq][j] = qp[j];
    }
    float4 oacc[2][4];
#pragma unroll
    for (int rq = 0; rq < 2; rq++)
#pragma unroll
        for (int j = 0; j < 4; j++) oacc[rq][j] = make_float4(0.f, 0.f, 0.f, 0.f);
    float lsum[2] = {0.f, 0.f};

    // wave's contiguous 512-row k-range; rows are wave-uniform addresses (broadcast loads)
    const float4* kp4 = (const float4*)(Kb + (long long)(w * 512) * DD);
    const float4* vp4 = (const float4*)(Vb + (long long)(w * 512) * DD);

    // A/B double-buffers: A=row0, B=row1 preloaded; refill at 2-row distance
    float4 kA[4], vA[4], kB[4], vB[4];
#pragma unroll
    for (int i = 0; i < 4; i++) { kA[i] = kp4[i]; vA[i] = vp4[i]; kB[i] = kp4[4 + i]; vB[i] = vp4[4 + i]; }

    for (int c = 0; c < 8; c++) {
        int kblk = w * 8 + c;
        unsigned long long mw0 = mrow[(long long)kblk * NN + qbase + lane];
        unsigned long long mw1 = mrow[(long long)kblk * NN + qbase + 64 + lane];
#pragma unroll 4
        for (int kk = 0; kk < 64; kk += 2) {
            int idx = c * 64 + kk;
#pragma unroll 2
            for (int par = 0; par < 2; par++) {
                // pull current row from its buffer, refill that buffer from row idx+2(+par).
                // last-iteration overread is <=3 rows past the wave's range: for the final
                // (b,h) it lands 64B into the next ws buffer (allocated, never read).
                float4 k0, k1, k2, k3, v0, v1, v2, v3;
                if (par == 0) {
                    k0 = kA[0]; k1 = kA[1]; k2 = kA[2]; k3 = kA[3];
                    v0 = vA[0]; v1 = vA[1]; v2 = vA[2]; v3 = vA[3];
#pragma unroll
                    for (int i = 0; i < 4; i++) { kA[i] = kp4[(idx + 2) * 4 + i]; vA[i] = vp4[(idx + 2) * 4 + i]; }
                } else {
                    k0 = kB[0]; k1 = kB[1]; k2 = kB[2]; k3 = kB[3];
                    v0 = vB[0]; v1 = vB[1]; v2 = vB[2]; v3 = vB[3];
#pragma unroll
                    for (int i = 0; i < 4; i++) { kB[i] = kp4[(idx + 3) * 4 + i]; vB[i] = vp4[(idx + 3) * 4 + i]; }
                }
                int bit = kk + par;
                float e[2];
#pragma unroll
                for (int rq = 0; rq < 2; rq++) {
                    float4 a0 = qf[rq][0], a1 = qf[rq][1], a2 = qf[rq][2], a3 = qf[rq][3];
                    float sA = a0.x * k0.x;
                    sA = fmaf(a0.y, k0.y, sA); sA = fmaf(a0.z, k0.z, sA); sA = fmaf(a0.w, k0.w, sA);
                    sA = fmaf(a1.x, k1.x, sA); sA = fmaf(a1.y, k1.y, sA); sA = fmaf(a1.z, k1.z, sA); sA = fmaf(a1.w, k1.w, sA);
                    float sB = a2.x * k2.x;
                    sB = fmaf(a2.y, k2.y, sB); sB = fmaf(a2.z, k2.z, sB); sB = fmaf(a2.w, k2.w, sB);
                    sB = fmaf(a3.x, k3.x, sB); sB = fmaf(a3.y, k3.y, sB); sB = fmaf(a3.z, k3.z, sB); sB = fmaf(a3.w, k3.w, sB);
                    float ee = __builtin_amdgcn_exp2f(sA + sB);     // softmax scale folded into Q
                    unsigned long long mwv = rq ? mw1 : mw0;
                    e[rq] = ((mwv >> bit) & 1ULL) ? 0.f : ee;
                    lsum[rq] += e[rq];
                }
#pragma unroll
                for (int rq = 0; rq < 2; rq++) {
                    float ew = e[rq];
                    oacc[rq][0].x = fmaf(ew, v0.x, oacc[rq][0].x); oacc[rq][0].y = fmaf(ew, v0.y, oacc[rq][0].y);
                    oacc[rq][0].z = fmaf(ew, v0.z, oacc[rq][0].z); oacc[rq][0].w = fmaf(ew, v0.w, oacc[rq][0].w);
                    oacc[rq][1].x = fmaf(ew, v1.x, oacc[rq][1].x); oacc[rq][1].y = fmaf(ew, v1.y, oacc[rq][1].y);
                    oacc[rq][1].z = fmaf(ew, v1.z, oacc[rq][1].z); oacc[rq][1].w = fmaf(ew, v1.w, oacc[rq][1].w);
                    oacc[rq][2].x = fmaf(ew, v2.x, oacc[rq][2].x); oacc[rq][2].y = fmaf(ew, v2.y, oacc[rq][2].y);
                    oacc[rq][2].z = fmaf(ew, v2.z, oacc[rq][2].z); oacc[rq][2].w = fmaf(ew, v2.w, oacc[rq][2].w);
                    oacc[rq][3].x = fmaf(ew, v3.x, oacc[rq][3].x); oacc[rq][3].y = fmaf(ew, v3.y, oacc[rq][3].y);
                    oacc[rq][3].z = fmaf(ew, v3.z, oacc[rq][3].z); oacc[rq][3].w = fmaf(ew, v3.w, oacc[rq][3].w);
                }
            }
        }
    }
    __syncthreads();
#pragma unroll
    for (int rq = 0; rq < 2; rq++) {
        float* rp = smem + (((w * 2 + rq) * 64 + lane)) * 17;   // stride 17: 2 lanes/bank, free
#pragma unroll
        for (int j = 0; j < 4; j++) {
            rp[4 * j + 0] = oacc[rq][j].x; rp[4 * j + 1] = oacc[rq][j].y;
            rp[4 * j + 2] = oacc[rq][j].z; rp[4 * j + 3] = oacc[rq][j].w;
        }
        rp[16] = lsum[rq];
    }
    __syncthreads();
    if (w < 2) {                                       // wave w combines q-group rq=w
        int rq = w;
        float acc[DD]; float lt = 0.f;
#pragma unroll
        for (int d = 0; d < DD; d++) acc[d] = 0.f;
#pragma unroll
        for (int p = 0; p < 4; p++) {
            const float* pp = smem + (((p * 2 + rq) * 64 + lane)) * 17;
#pragma unroll
            for (int d = 0; d < DD; d++) acc[d] += pp[d];
            lt += pp[16];
        }
        float inv = 1.0f / lt;
        int q = qbase + rq * 64 + lane;
        float* op = O + (long long)(b * NN + q) * EE + h * DD;
        float4 r0 = {acc[0]*inv, acc[1]*inv, acc[2]*inv, acc[3]*inv};
        float4 r1 = {acc[4]*inv, acc[5]*inv, acc[6]*inv, acc[7]*inv};
        float4 r2 = {acc[8]*inv, acc[9]*inv, acc[10]*inv, acc[11]*inv};
        float4 r3 = {acc[12]*inv, acc[13]*inv, acc[14]*inv, acc[15]*inv};
        ((float4*)op)[0] = r0; ((float4*)op)[1] = r1; ((float4*)op)[2] = r2; ((float4*)op)[3] = r3;
    }
}

// ---------------- out-projection + ReLU (standalone, used for layer 1) ----------------
__global__ __launch_bounds__(256) void k_out(const float* __restrict__ X, const float* __restrict__ WO,
                                             const float* __restrict__ bO, float* __restrict__ Y) {
    int lane = threadIdx.x & 63, quarter = threadIdx.x >> 6;
    long long row = (long long)blockIdx.x * 64 + lane;
    float xr[64];
    const float4* xp = (const float4*)(X + row * 64);
#pragma unroll
    for (int i = 0; i < 16; i++) {
        float4 t = xp[i];
        xr[4 * i] = t.x; xr[4 * i + 1] = t.y; xr[4 * i + 2] = t.z; xr[4 * i + 3] = t.w;
    }
    for (int jq = 0; jq < 4; jq++) {
        int j = quarter * 16 + jq * 4;
        float4 acc = *(const float4*)(bO + j);
#pragma unroll
        for (int f = 0; f < 64; f++) {
            float4 w4 = *(const float4*)(WO + f * 64 + j);
            acc.x = fmaf(xr[f], w4.x, acc.x);
            acc.y = fmaf(xr[f], w4.y, acc.y);
            acc.z = fmaf(xr[f], w4.z, acc.z);
            acc.w = fmaf(xr[f], w4.w, acc.w);
        }
        acc.x = fmaxf(acc.x, 0.f); acc.y = fmaxf(acc.y, 0.f);
        acc.z = fmaxf(acc.z, 0.f); acc.w = fmaxf(acc.w, 0.f);
        *(float4*)(Y + row * 64 + j) = acc;
    }
}

// ---------------- fused: out-proj(L0)+ReLU -> QKV proj (L1), x1 never touches HBM ----------------
__global__ __launch_bounds__(256) void k_outqkv(const float* __restrict__ O, const float* __restrict__ WO,
                                                const float* __restrict__ bO,
                                                const float* __restrict__ CW, const float* __restrict__ bQ,
                                                float* __restrict__ Q, float* __restrict__ K, float* __restrict__ V) {
    __shared__ float xs[64 * 68];
    int lane = threadIdx.x & 63, quarter = threadIdx.x >> 6;
    long long row = (long long)blockIdx.x * 64 + lane;
    int b = (int)(row >> 11), n = (int)(row & (NN - 1));
    {
        float xr[64];
        const float4* xp = (const float4*)(O + row * 64);
#pragma unroll
        for (int i = 0; i < 16; i++) {
            float4 t = xp[i];
            xr[4 * i] = t.x; xr[4 * i + 1] = t.y; xr[4 * i + 2] = t.z; xr[4 * i + 3] = t.w;
        }
        for (int jq = 0; jq < 4; jq++) {
            int j = quarter * 16 + jq * 4;
            float4 acc = *(const float4*)(bO + j);
#pragma unroll
            for (int f = 0; f < 64; f++) {
                float4 w4 = *(const float4*)(WO + f * 64 + j);
                acc.x = fmaf(xr[f], w4.x, acc.x);
                acc.y = fmaf(xr[f], w4.y, acc.y);
                acc.z = fmaf(xr[f], w4.z, acc.z);
                acc.w = fmaf(xr[f], w4.w, acc.w);
            }
            acc.x = fmaxf(acc.x, 0.f); acc.y = fmaxf(acc.y, 0.f);
            acc.z = fmaxf(acc.z, 0.f); acc.w = fmaxf(acc.w, 0.f);
            *(float4*)(xs + lane * 68 + j) = acc;
        }
    }
    __syncthreads();
    {
        float xr[64];
        const float4* xp = (const float4*)(xs + lane * 68);
#pragma unroll
        for (int i = 0; i < 16; i++) {
            float4 t = xp[i];
            xr[4 * i] = t.x; xr[4 * i + 1] = t.y; xr[4 * i + 2] = t.z; xr[4 * i + 3] = t.w;
        }
        for (int jq = 0; jq < 12; jq++) {
            int j = quarter * 48 + jq * 4;
            float4 acc = *(const float4*)(bQ + j);
#pragma unroll
            for (int f = 0; f < 64; f++) {
                float4 w4 = *(const float4*)(CW + f * 192 + j);
                acc.x = fmaf(xr[f], w4.x, acc.x);
                acc.y = fmaf(xr[f], w4.y, acc.y);
                acc.z = fmaf(xr[f], w4.z, acc.z);
                acc.w = fmaf(xr[f], w4.w, acc.w);
            }
            int which = j >> 6, c = j & 63, h = c >> 4, d = c & 15;
            float* dst = (which == 0) ? Q : ((which == 1) ? K : V);
            *(float4*)(dst + (((long long)(b * HH + h) * NN + n) * DD + d)) = acc;
        }
    }
}

// ---------------- fused 3-layer MLP head v2: 2-pass stage2, padded LDS ----------------
__global__ __launch_bounds__(128) void k_head(const float* __restrict__ X,
                                              const float* __restrict__ w1, const float* __restrict__ b1,
                                              const float* __restrict__ w2, const float* __restrict__ b2,
                                              const float* __restrict__ w3, const float* __restrict__ b3,
                                              float* __restrict__ out) {
    __shared__ float Xs[16 * 64];
    __shared__ float H1[16 * 132];
    __shared__ float H2[16 * 132];
    int tid = threadIdx.x;
    long long row0 = (long long)blockIdx.x * 16;
    {
        const float4* src = (const float4*)(X + row0 * 64);
        float4* dst = (float4*)Xs;
        dst[tid] = src[tid];
        dst[tid + 128] = src[tid + 128];
    }
    __syncthreads();
    {
        float wr[64];
#pragma unroll
        for (int f = 0; f < 64; f++) wr[f] = w1[f * 128 + tid];
        float bb = b1[tid];
        for (int r = 0; r < 16; r++) {
            const float4* x4 = (const float4*)(Xs + r * 64);
            float a0 = bb, a1 = 0.f, a2 = 0.f, a3 = 0.f;
#pragma unroll
            for (int fq = 0; fq < 16; fq++) {
                float4 xv = x4[fq];
                a0 = fmaf(xv.x, wr[4 * fq], a0);
                a1 = fmaf(xv.y, wr[4 * fq + 1], a1);
                a2 = fmaf(xv.z, wr[4 * fq + 2], a2);
                a3 = fmaf(xv.w, wr[4 * fq + 3], a3);
            }
            H1[r * 132 + tid] = fmaxf((a0 + a1) + (a2 + a3), 0.f);
        }
    }
    __syncthreads();
    {
        float acc2[16];
        float bb2 = b2[tid];
#pragma unroll
        for (int r = 0; r < 16; r++) acc2[r] = bb2;
#pragma unroll
        for (int p = 0; p < 2; p++) {
            float wr2[64];
#pragma unroll
            for (int i = 0; i < 64; i++) wr2[i] = w2[(p * 64 + i) * 128 + tid];
            for (int r = 0; r < 16; r++) {
                const float4* h4 = (const float4*)(H1 + r * 132 + p * 64);
                float a0 = 0.f, a1 = 0.f, a2 = 0.f, a3 = 0.f;
#pragma unroll
                for (int fq = 0; fq < 16; fq++) {
                    float4 xv = h4[fq];
                    a0 = fmaf(xv.x, wr2[4 * fq], a0);
                    a1 = fmaf(xv.y, wr2[4 * fq + 1], a1);
                    a2 = fmaf(xv.z, wr2[4 * fq + 2], a2);
                    a3 = fmaf(xv.w, wr2[4 * fq + 3], a3);
                }
                acc2[r] += (a0 + a1) + (a2 + a3);
            }
        }
#pragma unroll
        for (int r = 0; r < 16; r++) H2[r * 132 + tid] = fmaxf(acc2[r], 0.f);
    }
    __syncthreads();
    if (tid < 64) {
        int r = tid >> 2, a = tid & 3;
        float acc = b3[a];
        for (int f = 0; f < 128; f++) acc = fmaf(H2[r * 132 + f], w3[f * 4 + a], acc);
        out[(row0 + r) * 4 + a] = acc;
    }
}

extern "C" void kernel_launch(void* const* d_in, const int* in_sizes, int n_in,
                              void* d_out, int out_size, void* d_ws, size_t ws_size,
                              hipStream_t stream) {
    const float* nf = (const float*)d_in[0];
    const float* adj = (const float*)d_in[1];
    const float* l0[9]; for (int i = 0; i < 9; i++) l0[i] = (const float*)d_in[2 + i];
    const float* l1[9]; for (int i = 0; i < 9; i++) l1[i] = (const float*)d_in[11 + i];
    const float* hw1 = (const float*)d_in[20]; const float* hb1 = (const float*)d_in[21];
    const float* hw2 = (const float*)d_in[22]; const float* hb2 = (const float*)d_in[23];
    const float* hw3 = (const float*)d_in[24]; const float* hb3 = (const float*)d_in[25];
    float* out = (float*)d_out;

    char* ws = (char*)d_ws;
    size_t off = 0;
    auto alloc = [&](size_t bytes) -> void* {
        void* p = ws + off;
        off = (off + bytes + 255) & ~(size_t)255;
        return p;
    };
    unsigned long long* mbT = (unsigned long long*)alloc((size_t)BB * NN * NN / 8);
    float* Q = (float*)alloc((size_t)BB * HH * NN * DD * 4);
    float* K = (float*)alloc((size_t)BB * HH * NN * DD * 4);
    float* V = (float*)alloc((size_t)BB * HH * NN * DD * 4);
    float* O = (float*)alloc((size_t)BB * NN * EE * 4);
    float* x2 = (float*)alloc((size_t)BB * NN * EE * 4);
    float* CW0 = (float*)alloc(16 * 192 * 4);
    float* CW1 = (float*)alloc(64 * 192 * 4);
    float* WO0 = (float*)alloc(64 * 64 * 4);
    float* WO1 = (float*)alloc(64 * 64 * 4);
    float* bO0 = (float*)alloc(64 * 4);
    float* bO1 = (float*)alloc(64 * 4);
    float* bQ0 = (float*)alloc(192 * 4);
    float* bQ1 = (float*)alloc(192 * 4);

    k_mask<<<4096, 256, 0, stream>>>(adj, mbT);
    k_wcomb<<<dim3(65, 2), 256, 0, stream>>>(
        l0[0], l0[1], l0[2], l0[3], l0[4], l0[5], l0[6], l0[7], l0[8],
        l1[0], l1[1], l1[2], l1[3], l1[4], l1[5], l1[6], l1[7], l1[8],
        CW0, WO0, bO0, bQ0, CW1, WO1, bO1, bQ1);

    // layer 0 (feature scale folded into CW0)
    k_qkv<16><<<BB * NN / 64, 256, 0, stream>>>(nf, CW0, bQ0, Q, K, V);
    k_attn<<<dim3(NN / 128, HH, BB), 256, 0, stream>>>(Q, K, V, mbT, O);
    // fused: out-proj L0 + QKV proj L1
    k_outqkv<<<BB * NN / 64, 256, 0, stream>>>(O, WO0, bO0, CW1, bQ1, Q, K, V);
    k_attn<<<dim3(NN / 128, HH, BB), 256, 0, stream>>>(Q, K, V, mbT, O);
    k_out<<<BB * NN / 64, 256, 0, stream>>>(O, WO1, bO1, x2);
    // head
    k_head<<<BB * NN / 16, 128, 0, stream>>>(x2, hw1, hb1, hw2, hb2, hw3, hb3, out);
}

// Round 9
// 588.554 us; speedup vs baseline: 1.4423x; 1.4423x over previous
//
#include <hip/hip_runtime.h>

#define BB 8
#define NN 2048
#define FIN0 16
#define EE 64
#define HH 4
#define DD 16
#define HIDN 128
#define AA 4

// ---------------- adjacency -> blocked bitmask, TRANSPOSED: mbT[b][kblk][q] ----------------
__global__ __launch_bounds__(256) void k_mask(const float* __restrict__ adj, unsigned long long* __restrict__ mbT) {
    const int ITER = 32;
    for (int it = 0; it < ITER; it++) {
        long long idx = ((long long)blockIdx.x * ITER + it) * 256 + threadIdx.x;  // b*N*N + r*N + k
        int k = (int)(idx & (NN - 1));
        int r = (int)((idx >> 11) & (NN - 1));
        int b = (int)(idx >> 22);
        float a = adj[idx];
        bool blocked = (a == 0.0f) && (k != r);
        unsigned long long m = __ballot(blocked);
        if ((threadIdx.x & 63) == 0) mbT[((long long)b * 32 + (k >> 6)) * NN + r] = m;
    }
}

// ---------------- fold weights: CW = {wq,wk,wv}@in_w (Q cols pre-scaled), WO = mha_ow@op_w ----------------
#define QSCALE 0.36067376022224085f   // 0.25 * log2(e)
__device__ __forceinline__ float sfeat(int f) {
    return (f == 4 || f == 14 || f == 15) ? 1.0f : ((f == 5) ? (1.0f / 300.0f) : 0.02f);
}
__global__ __launch_bounds__(256) void k_wcomb(
        const float* __restrict__ wq0, const float* __restrict__ wk0, const float* __restrict__ wv0,
        const float* __restrict__ inw0, const float* __restrict__ inb0,
        const float* __restrict__ mow0, const float* __restrict__ mob0,
        const float* __restrict__ opw0, const float* __restrict__ opb0,
        const float* __restrict__ wq1, const float* __restrict__ wk1, const float* __restrict__ wv1,
        const float* __restrict__ inw1, const float* __restrict__ inb1,
        const float* __restrict__ mow1, const float* __restrict__ mob1,
        const float* __restrict__ opw1, const float* __restrict__ opb1,
        float* __restrict__ CW0, float* __restrict__ WO0, float* __restrict__ bO0, float* __restrict__ bQ0,
        float* __restrict__ CW1, float* __restrict__ WO1, float* __restrict__ bO1, float* __restrict__ bQ1) {
    int ly = blockIdx.y;
    int fin = ly ? EE : FIN0;
    const float* wq = ly ? wq1 : wq0; const float* wk = ly ? wk1 : wk0; const float* wv = ly ? wv1 : wv0;
    const float* inw = ly ? inw1 : inw0; const float* inb = ly ? inb1 : inb0;
    const float* mow = ly ? mow1 : mow0; const float* mob = ly ? mob1 : mob0;
    const float* opw = ly ? opw1 : opw0; const float* opb = ly ? opb1 : opb0;
    float* CW = ly ? CW1 : CW0; float* WO = ly ? WO1 : WO0;
    float* bO = ly ? bO1 : bO0; float* bQ = ly ? bQ1 : bQ0;

    int t = blockIdx.x * 256 + threadIdx.x;
    int t1 = fin * 192;
    int t2 = t1 + 4096;
    int t3 = t2 + 64;
    int t4 = t3 + 192;
    if (t < t1) {
        int f = t / 192, j = t % 192;
        const float* w = (j < 64) ? wq : ((j < 128) ? wk : wv);
        float acc = 0.f;
        for (int kk = 0; kk < 64; kk++) acc += w[f * 64 + kk] * inw[kk * 192 + j];
        if (j < 64) acc *= QSCALE;
        if (ly == 0) acc *= sfeat(f);
        CW[t] = acc;
    } else if (t < t2) {
        int u = t - t1; int i = u >> 6, j = u & 63;
        float acc = 0.f;
        for (int kk = 0; kk < 64; kk++) acc += mow[i * 64 + kk] * opw[kk * 64 + j];
        WO[u] = acc;
    } else if (t < t3) {
        int j = t - t2;
        float acc = opb[j];
        for (int kk = 0; kk < 64; kk++) acc += mob[kk] * opw[kk * 64 + j];
        bO[j] = acc;
    } else if (t < t4) {
        int j = t - t3;
        bQ[j] = inb[j] * ((j < 64) ? QSCALE : 1.0f);
    }
}

// ---------------- fused QKV projection (layer 0): X[B*N][fin] @ CW + bQ -> Q,K,V [B][H][N][D] ----------------
template <int FINP>
__global__ __launch_bounds__(256) void k_qkv(const float* __restrict__ X, const float* __restrict__ CW,
                                             const float* __restrict__ bQ,
                                             float* __restrict__ Q, float* __restrict__ K, float* __restrict__ V) {
    int lane = threadIdx.x & 63;
    int quarter = threadIdx.x >> 6;
    int row = blockIdx.x * 64 + lane;
    int b = row >> 11, n = row & (NN - 1);
    float xr[FINP];
    const float4* xp = (const float4*)(X + (long long)row * FINP);
#pragma unroll
    for (int i = 0; i < FINP / 4; i++) {
        float4 v = xp[i];
        xr[4 * i] = v.x; xr[4 * i + 1] = v.y; xr[4 * i + 2] = v.z; xr[4 * i + 3] = v.w;
    }
    for (int jq = 0; jq < 12; jq++) {
        int j = quarter * 48 + jq * 4;
        float4 acc = *(const float4*)(bQ + j);
#pragma unroll
        for (int f = 0; f < FINP; f++) {
            float4 w = *(const float4*)(CW + f * 192 + j);
            acc.x = fmaf(xr[f], w.x, acc.x);
            acc.y = fmaf(xr[f], w.y, acc.y);
            acc.z = fmaf(xr[f], w.z, acc.z);
            acc.w = fmaf(xr[f], w.w, acc.w);
        }
        int which = j >> 6, c = j & 63, h = c >> 4, d = c & 15;
        float* dst = (which == 0) ? Q : ((which == 1) ? K : V);
        *(float4*)(dst + (((long long)(b * HH + h) * NN + n) * DD + d)) = acc;
    }
}

// ---------------- attention v4 (RESTORED — best measured: 139.8 µs/dispatch) ----------------
// 256 q-rows/block (4/lane), 8-way k-split, wave-private LDS staging with register prefetch
// of the next chunk (K/V/mask); no per-chunk barriers (intra-wave lgkmcnt only).
// R=4 is the register-feasible optimum: qf 64 + oacc 64 = 128 VGPR = the allocator's hard
// ceiling for 512-thr blocks (v5-v8 all proved bigger register footprints spill or collapse).
__global__ __launch_bounds__(512, 2) void k_attn(const float* __restrict__ Q, const float* __restrict__ K,
                                                 const float* __restrict__ V,
                                                 const unsigned long long* __restrict__ mbT,
                                                 float* __restrict__ O) {
    __shared__ float smem[8 * 4 * 64 * 17];            // stage region overlaid by reduction region
    int lane = threadIdx.x & 63;
    int w = threadIdx.x >> 6;                          // k-eighth owner
    int qb = blockIdx.x, h = blockIdx.y, b = blockIdx.z;
    int qbase = qb * 256;

    const float* Qbh = Q + (long long)(b * HH + h) * NN * DD;
    const float* Kb  = K + (long long)(b * HH + h) * NN * DD;
    const float* Vb  = V + (long long)(b * HH + h) * NN * DD;
    const unsigned long long* mrow = mbT + (long long)b * 32 * NN;

    float4 qf[4][4];
#pragma unroll
    for (int rq = 0; rq < 4; rq++) {
        const float4* qp = (const float4*)(Qbh + (long long)(qbase + rq * 64 + lane) * DD);
#pragma unroll
        for (int j = 0; j < 4; j++) qf[rq][j] = qp[j];
    }
    float4 oacc[4][4];
#pragma unroll
    for (int rq = 0; rq < 4; rq++)
#pragma unroll
        for (int j = 0; j < 4; j++) oacc[rq][j] = make_float4(0.f, 0.f, 0.f, 0.f);
    float lsum[4] = {0.f, 0.f, 0.f, 0.f};

    float* sK = smem + w * 2048;
    float* sV = sK + 1024;

    // prologue: prefetch chunk 0 into registers
    float4 kpre[4], vpre[4];
    unsigned long long mwpre[4];
    {
        const float4* srcK = (const float4*)(Kb + (long long)(w * 256) * DD);
        const float4* srcV = (const float4*)(Vb + (long long)(w * 256) * DD);
#pragma unroll
        for (int i = 0; i < 4; i++) { kpre[i] = srcK[lane + 64 * i]; vpre[i] = srcV[lane + 64 * i]; }
#pragma unroll
        for (int rq = 0; rq < 4; rq++) mwpre[rq] = mrow[(long long)(w * 4) * NN + qbase + rq * 64 + lane];
    }

#pragma unroll
    for (int c = 0; c < 4; c++) {
        // stage prefetched chunk into wave-private LDS
#pragma unroll
        for (int i = 0; i < 4; i++) {
            ((float4*)sK)[lane + 64 * i] = kpre[i];
            ((float4*)sV)[lane + 64 * i] = vpre[i];
        }
        unsigned long long mw[4];
#pragma unroll
        for (int rq = 0; rq < 4; rq++) mw[rq] = mwpre[rq];
        // issue next chunk's loads; they complete during the inner loop below
        if (c < 3) {
            int kcn = w * 256 + (c + 1) * 64;
            const float4* srcK = (const float4*)(Kb + (long long)kcn * DD);
            const float4* srcV = (const float4*)(Vb + (long long)kcn * DD);
#pragma unroll
            for (int i = 0; i < 4; i++) { kpre[i] = srcK[lane + 64 * i]; vpre[i] = srcV[lane + 64 * i]; }
            int kblkn = w * 4 + c + 1;
#pragma unroll
            for (int rq = 0; rq < 4; rq++) mwpre[rq] = mrow[(long long)kblkn * NN + qbase + rq * 64 + lane];
        }
        // make this wave's LDS writes visible to its own lanes (wave-private -> no barrier)
        asm volatile("s_waitcnt lgkmcnt(0)" ::: "memory");
#pragma unroll 4
        for (int kk = 0; kk < 64; kk++) {
            const float4* kr = (const float4*)(sK + kk * 16);
            float4 k0 = kr[0], k1 = kr[1], k2 = kr[2], k3 = kr[3];
            float e[4];
#pragma unroll
            for (int rq = 0; rq < 4; rq++) {
                float4 a0 = qf[rq][0], a1 = qf[rq][1], a2 = qf[rq][2], a3 = qf[rq][3];
                float sA = a0.x * k0.x;
                sA = fmaf(a0.y, k0.y, sA); sA = fmaf(a0.z, k0.z, sA); sA = fmaf(a0.w, k0.w, sA);
                sA = fmaf(a1.x, k1.x, sA); sA = fmaf(a1.y, k1.y, sA); sA = fmaf(a1.z, k1.z, sA); sA = fmaf(a1.w, k1.w, sA);
                float sB = a2.x * k2.x;
                sB = fmaf(a2.y, k2.y, sB); sB = fmaf(a2.z, k2.z, sB); sB = fmaf(a2.w, k2.w, sB);
                sB = fmaf(a3.x, k3.x, sB); sB = fmaf(a3.y, k3.y, sB); sB = fmaf(a3.z, k3.z, sB); sB = fmaf(a3.w, k3.w, sB);
                float ee = __builtin_amdgcn_exp2f(sA + sB);     // softmax scale folded into Q
                e[rq] = ((mw[rq] >> kk) & 1ULL) ? 0.f : ee;
                lsum[rq] += e[rq];
            }
            const float4* vr = (const float4*)(sV + kk * 16);
            float4 v0 = vr[0], v1 = vr[1], v2 = vr[2], v3 = vr[3];
#pragma unroll
            for (int rq = 0; rq < 4; rq++) {
                float ew = e[rq];
                oacc[rq][0].x = fmaf(ew, v0.x, oacc[rq][0].x); oacc[rq][0].y = fmaf(ew, v0.y, oacc[rq][0].y);
                oacc[rq][0].z = fmaf(ew, v0.z, oacc[rq][0].z); oacc[rq][0].w = fmaf(ew, v0.w, oacc[rq][0].w);
                oacc[rq][1].x = fmaf(ew, v1.x, oacc[rq][1].x); oacc[rq][1].y = fmaf(ew, v1.y, oacc[rq][1].y);
                oacc[rq][1].z = fmaf(ew, v1.z, oacc[rq][1].z); oacc[rq][1].w = fmaf(ew, v1.w, oacc[rq][1].w);
                oacc[rq][2].x = fmaf(ew, v2.x, oacc[rq][2].x); oacc[rq][2].y = fmaf(ew, v2.y, oacc[rq][2].y);
                oacc[rq][2].z = fmaf(ew, v2.z, oacc[rq][2].z); oacc[rq][2].w = fmaf(ew, v2.w, oacc[rq][2].w);
                oacc[rq][3].x = fmaf(ew, v3.x, oacc[rq][3].x); oacc[rq][3].y = fmaf(ew, v3.y, oacc[rq][3].y);
                oacc[rq][3].z = fmaf(ew, v3.z, oacc[rq][3].z); oacc[rq][3].w = fmaf(ew, v3.w, oacc[rq][3].w);
            }
        }
    }
    __syncthreads();                                   // all staging reads done before overlay
#pragma unroll
    for (int rq = 0; rq < 4; rq++) {
        float* rp = smem + (((w * 4 + rq) * 64 + lane)) * 17;   // stride 17: 2 lanes/bank, free
#pragma unroll
        for (int j = 0; j < 4; j++) {
            rp[4 * j + 0] = oacc[rq][j].x; rp[4 * j + 1] = oacc[rq][j].y;
            rp[4 * j + 2] = oacc[rq][j].z; rp[4 * j + 3] = oacc[rq][j].w;
        }
        rp[16] = lsum[rq];
    }
    __syncthreads();
    if (w < 4) {
        int rq = w;
        float acc[DD]; float lt = 0.f;
#pragma unroll
        for (int d = 0; d < DD; d++) acc[d] = 0.f;
#pragma unroll
        for (int p = 0; p < 8; p++) {
            const float* pp = smem + (((p * 4 + rq) * 64 + lane)) * 17;
#pragma unroll
            for (int d = 0; d < DD; d++) acc[d] += pp[d];
            lt += pp[16];
        }
        float inv = 1.0f / lt;
        int q = qbase + rq * 64 + lane;
        float* op = O + (long long)(b * NN + q) * EE + h * DD;
        float4 r0 = {acc[0]*inv, acc[1]*inv, acc[2]*inv, acc[3]*inv};
        float4 r1 = {acc[4]*inv, acc[5]*inv, acc[6]*inv, acc[7]*inv};
        float4 r2 = {acc[8]*inv, acc[9]*inv, acc[10]*inv, acc[11]*inv};
        float4 r3 = {acc[12]*inv, acc[13]*inv, acc[14]*inv, acc[15]*inv};
        ((float4*)op)[0] = r0; ((float4*)op)[1] = r1; ((float4*)op)[2] = r2; ((float4*)op)[3] = r3;
    }
}

// ---------------- fused: out-proj(L0)+ReLU -> QKV proj (L1), x1 never touches HBM ----------------
__global__ __launch_bounds__(256) void k_outqkv(const float* __restrict__ O, const float* __restrict__ WO,
                                                const float* __restrict__ bO,
                                                const float* __restrict__ CW, const float* __restrict__ bQ,
                                                float* __restrict__ Q, float* __restrict__ K, float* __restrict__ V) {
    __shared__ float xs[64 * 68];
    int lane = threadIdx.x & 63, quarter = threadIdx.x >> 6;
    long long row = (long long)blockIdx.x * 64 + lane;
    int b = (int)(row >> 11), n = (int)(row & (NN - 1));
    {
        float xr[64];
        const float4* xp = (const float4*)(O + row * 64);
#pragma unroll
        for (int i = 0; i < 16; i++) {
            float4 t = xp[i];
            xr[4 * i] = t.x; xr[4 * i + 1] = t.y; xr[4 * i + 2] = t.z; xr[4 * i + 3] = t.w;
        }
        for (int jq = 0; jq < 4; jq++) {
            int j = quarter * 16 + jq * 4;
            float4 acc = *(const float4*)(bO + j);
#pragma unroll
            for (int f = 0; f < 64; f++) {
                float4 w4 = *(const float4*)(WO + f * 64 + j);
                acc.x = fmaf(xr[f], w4.x, acc.x);
                acc.y = fmaf(xr[f], w4.y, acc.y);
                acc.z = fmaf(xr[f], w4.z, acc.z);
                acc.w = fmaf(xr[f], w4.w, acc.w);
            }
            acc.x = fmaxf(acc.x, 0.f); acc.y = fmaxf(acc.y, 0.f);
            acc.z = fmaxf(acc.z, 0.f); acc.w = fmaxf(acc.w, 0.f);
            *(float4*)(xs + lane * 68 + j) = acc;
        }
    }
    __syncthreads();
    {
        float xr[64];
        const float4* xp = (const float4*)(xs + lane * 68);
#pragma unroll
        for (int i = 0; i < 16; i++) {
            float4 t = xp[i];
            xr[4 * i] = t.x; xr[4 * i + 1] = t.y; xr[4 * i + 2] = t.z; xr[4 * i + 3] = t.w;
        }
        for (int jq = 0; jq < 12; jq++) {
            int j = quarter * 48 + jq * 4;
            float4 acc = *(const float4*)(bQ + j);
#pragma unroll
            for (int f = 0; f < 64; f++) {
                float4 w4 = *(const float4*)(CW + f * 192 + j);
                acc.x = fmaf(xr[f], w4.x, acc.x);
                acc.y = fmaf(xr[f], w4.y, acc.y);
                acc.z = fmaf(xr[f], w4.z, acc.z);
                acc.w = fmaf(xr[f], w4.w, acc.w);
            }
            int which = j >> 6, c = j & 63, h = c >> 4, d = c & 15;
            float* dst = (which == 0) ? Q : ((which == 1) ? K : V);
            *(float4*)(dst + (((long long)(b * HH + h) * NN + n) * DD + d)) = acc;
        }
    }
}

// ---------------- fused: out-proj(L1)+ReLU -> 3-layer MLP head (x2 never touches HBM) ----------------
__global__ __launch_bounds__(128) void k_outhead(const float* __restrict__ O,
                                                 const float* __restrict__ WO, const float* __restrict__ bO,
                                                 const float* __restrict__ w1, const float* __restrict__ b1,
                                                 const float* __restrict__ w2, const float* __restrict__ b2,
                                                 const float* __restrict__ w3, const float* __restrict__ b3,
                                                 float* __restrict__ out) {
    __shared__ float Xs[16 * 64];                      // attn-L1 output rows
    __shared__ float X2s[16 * 68];                     // after out-proj+ReLU (stride 68: 16B-aligned)
    __shared__ float H1[16 * 132];
    __shared__ float H2[16 * 132];
    int tid = threadIdx.x;
    long long row0 = (long long)blockIdx.x * 16;
    {
        const float4* src = (const float4*)(O + row0 * 64);
        float4* dst = (float4*)Xs;
        dst[tid] = src[tid];
        dst[tid + 128] = src[tid + 128];
    }
    __syncthreads();
    // stage 0: out-proj + ReLU. col = tid&63, row-half = tid>>6 (8 rows each).
    {
        int col = tid & 63;
        float wr[64];
#pragma unroll
        for (int f = 0; f < 64; f++) wr[f] = WO[f * 64 + col];
        float bb = bO[col];
#pragma unroll
        for (int rr = 0; rr < 8; rr++) {
            int r = (tid >> 6) * 8 + rr;
            const float4* x4 = (const float4*)(Xs + r * 64);
            float a0 = bb, a1 = 0.f, a2 = 0.f, a3 = 0.f;
#pragma unroll
            for (int fq = 0; fq < 16; fq++) {
                float4 xv = x4[fq];
                a0 = fmaf(xv.x, wr[4 * fq], a0);
                a1 = fmaf(xv.y, wr[4 * fq + 1], a1);
                a2 = fmaf(xv.z, wr[4 * fq + 2], a2);
                a3 = fmaf(xv.w, wr[4 * fq + 3], a3);
            }
            X2s[r * 68 + col] = fmaxf((a0 + a1) + (a2 + a3), 0.f);
        }
    }
    __syncthreads();
    // stage 1: h1 = relu(x2@w1 + b1), col = tid
    {
        float wr[64];
#pragma unroll
        for (int f = 0; f < 64; f++) wr[f] = w1[f * 128 + tid];
        float bb = b1[tid];
        for (int r = 0; r < 16; r++) {
            const float4* x4 = (const float4*)(X2s + r * 68);
            float a0 = bb, a1 = 0.f, a2 = 0.f, a3 = 0.f;
#pragma unroll
            for (int fq = 0; fq < 16; fq++) {
                float4 xv = x4[fq];
                a0 = fmaf(xv.x, wr[4 * fq], a0);
                a1 = fmaf(xv.y, wr[4 * fq + 1], a1);
                a2 = fmaf(xv.z, wr[4 * fq + 2], a2);
                a3 = fmaf(xv.w, wr[4 * fq + 3], a3);
            }
            H1[r * 132 + tid] = fmaxf((a0 + a1) + (a2 + a3), 0.f);
        }
    }
    __syncthreads();
    // stage 2: h2 = relu(h1@w2 + b2) — two passes so the w2-column cache is 64 regs
    {
        float acc2[16];
        float bb2 = b2[tid];
#pragma unroll
        for (int r = 0; r < 16; r++) acc2[r] = bb2;
#pragma unroll
        for (int p = 0; p < 2; p++) {
            float wr2[64];
#pragma unroll
            for (int i = 0; i < 64; i++) wr2[i] = w2[(p * 64 + i) * 128 + tid];
            for (int r = 0; r < 16; r++) {
                const float4* h4 = (const float4*)(H1 + r * 132 + p * 64);
                float a0 = 0.f, a1 = 0.f, a2 = 0.f, a3 = 0.f;
#pragma unroll
                for (int fq = 0; fq < 16; fq++) {
                    float4 xv = h4[fq];
                    a0 = fmaf(xv.x, wr2[4 * fq], a0);
                    a1 = fmaf(xv.y, wr2[4 * fq + 1], a1);
                    a2 = fmaf(xv.z, wr2[4 * fq + 2], a2);
                    a3 = fmaf(xv.w, wr2[4 * fq + 3], a3);
                }
                acc2[r] += (a0 + a1) + (a2 + a3);
            }
        }
#pragma unroll
        for (int r = 0; r < 16; r++) H2[r * 132 + tid] = fmaxf(acc2[r], 0.f);
    }
    __syncthreads();
    // stage 3: out = h2@w3 + b3 (A=4)
    if (tid < 64) {
        int r = tid >> 2, a = tid & 3;
        float acc = b3[a];
        for (int f = 0; f < 128; f++) acc = fmaf(H2[r * 132 + f], w3[f * 4 + a], acc);
        out[(row0 + r) * 4 + a] = acc;
    }
}

extern "C" void kernel_launch(void* const* d_in, const int* in_sizes, int n_in,
                              void* d_out, int out_size, void* d_ws, size_t ws_size,
                              hipStream_t stream) {
    const float* nf = (const float*)d_in[0];
    const float* adj = (const float*)d_in[1];
    const float* l0[9]; for (int i = 0; i < 9; i++) l0[i] = (const float*)d_in[2 + i];
    const float* l1[9]; for (int i = 0; i < 9; i++) l1[i] = (const float*)d_in[11 + i];
    const float* hw1 = (const float*)d_in[20]; const float* hb1 = (const float*)d_in[21];
    const float* hw2 = (const float*)d_in[22]; const float* hb2 = (const float*)d_in[23];
    const float* hw3 = (const float*)d_in[24]; const float* hb3 = (const float*)d_in[25];
    float* out = (float*)d_out;

    char* ws = (char*)d_ws;
    size_t off = 0;
    auto alloc = [&](size_t bytes) -> void* {
        void* p = ws + off;
        off = (off + bytes + 255) & ~(size_t)255;
        return p;
    };
    unsigned long long* mbT = (unsigned long long*)alloc((size_t)BB * NN * NN / 8);
    float* Q = (float*)alloc((size_t)BB * HH * NN * DD * 4);   // follows mbT: absorbs mask prefetch overread
    float* K = (float*)alloc((size_t)BB * HH * NN * DD * 4);
    float* V = (float*)alloc((size_t)BB * HH * NN * DD * 4);
    float* O = (float*)alloc((size_t)BB * NN * EE * 4);        // follows V: absorbs V prefetch overread
    float* CW0 = (float*)alloc(16 * 192 * 4);
    float* CW1 = (float*)alloc(64 * 192 * 4);
    float* WO0 = (float*)alloc(64 * 64 * 4);
    float* WO1 = (float*)alloc(64 * 64 * 4);
    float* bO0 = (float*)alloc(64 * 4);
    float* bO1 = (float*)alloc(64 * 4);
    float* bQ0 = (float*)alloc(192 * 4);
    float* bQ1 = (float*)alloc(192 * 4);

    k_mask<<<4096, 256, 0, stream>>>(adj, mbT);
    k_wcomb<<<dim3(65, 2), 256, 0, stream>>>(
        l0[0], l0[1], l0[2], l0[3], l0[4], l0[5], l0[6], l0[7], l0[8],
        l1[0], l1[1], l1[2], l1[3], l1[4], l1[5], l1[6], l1[7], l1[8],
        CW0, WO0, bO0, bQ0, CW1, WO1, bO1, bQ1);

    // layer 0 (feature scale folded into CW0)
    k_qkv<16><<<BB * NN / 64, 256, 0, stream>>>(nf, CW0, bQ0, Q, K, V);
    k_attn<<<dim3(NN / 256, HH, BB), 512, 0, stream>>>(Q, K, V, mbT, O);
    // fused: out-proj L0 + QKV proj L1
    k_outqkv<<<BB * NN / 64, 256, 0, stream>>>(O, WO0, bO0, CW1, bQ1, Q, K, V);
    k_attn<<<dim3(NN / 256, HH, BB), 512, 0, stream>>>(Q, K, V, mbT, O);
    // fused: out-proj L1 + MLP head
    k_outhead<<<BB * NN / 16, 128, 0, stream>>>(O, WO1, bO1, hw1, hb1, hw2, hb2, hw3, hb3, out);
}